// Round 5
// baseline (1862.475 us; speedup 1.0000x reference)
//
#include <hip/hip_runtime.h>

// LSTM_26912265077001: 2-layer LSTM (H=51, IN=1), T=512, B=1024, fp32.
// R5: abandon register-resident weights (R1-R4 all ~110 VGPR / ~1.4 ms: the
// backend refuses to keep 153 weight floats live no matter what). New
// structure: weights staged ONCE into LDS, streamed each step; NB=4 batch
// per block, grid=256 = 1 block/CU (minimizes per-CU weight LDS traffic:
// 127 KB/step/CU). Weight reads are per-lane ds_read_b128 at row stride 52
// words (balanced banks); h reads are wave-uniform broadcasts; each weight
// float4 read feeds 16 FMAs.

#define Hs   51
#define HP   52          // padded row length (pad always 0)
#define K4   13          // HP/4 float4 chunks
#define G4   204         // 4*H gate rows
#define Ts   512
#define Bs   1024
#define NB   4           // batch elements per block
#define NT   256

__device__ __forceinline__ float sig_(float x) {
    return 1.0f / (1.0f + __expf(-x));
}
__device__ __forceinline__ float tanh_(float x) {
    float e = __expf(2.0f * x);
    return 1.0f - 2.0f / (e + 1.0f);
}

__global__ void __launch_bounds__(NT) lstm2_kernel(
    const float* __restrict__ x,      // (T, B, 1)
    const float* __restrict__ W_ih1,  // (204, 1)
    const float* __restrict__ W_hh1,  // (204, 51)
    const float* __restrict__ b_ih1,  // (204,)
    const float* __restrict__ b_hh1,  // (204,)
    const float* __restrict__ W_ih2,  // (204, 51)
    const float* __restrict__ W_hh2,  // (204, 51)
    const float* __restrict__ b_ih2,  // (204,)
    const float* __restrict__ b_hh2,  // (204,)
    const float* __restrict__ W_lin,  // (1, 51)
    const float* __restrict__ b_lin,  // (1,)
    float* __restrict__ out)          // (B, T)
{
    __shared__ float4 w1L[G4 * K4];   // W_hh1 rows, padded      (42.4 KB)
    __shared__ float4 w2L[G4 * K4];   // W_ih2 rows              (42.4 KB)
    __shared__ float4 w3L[G4 * K4];   // W_hh2 rows              (42.4 KB)
    __shared__ float  xs[Ts][NB];     // input slice             ( 8.0 KB)
    __shared__ float4 h14[NB][K4];    // layer-1 hidden
    __shared__ float4 h24[NB][K4];    // layer-2 hidden
    __shared__ float  gs[NB][G4];     // gate pre-activations
    __shared__ float4 wlin4[K4];
    __shared__ float  blin_s;

    const int tid = threadIdx.x;
    const int bg0 = blockIdx.x * NB;

    // ---- one-time staging ----
    for (int idx = tid; idx < Ts * NB; idx += NT) {
        int t = idx >> 2, b = idx & 3;
        xs[t][b] = x[t * Bs + bg0 + b];
    }
    for (int idx = tid; idx < G4 * HP; idx += NT) {
        int r = idx / HP, k = idx - r * HP;
        float v1 = (k < Hs) ? W_hh1[r * Hs + k] : 0.f;
        float v2 = (k < Hs) ? W_ih2[r * Hs + k] : 0.f;
        float v3 = (k < Hs) ? W_hh2[r * Hs + k] : 0.f;
        ((float*)w1L)[idx] = v1;
        ((float*)w2L)[idx] = v2;
        ((float*)w3L)[idx] = v3;
    }
    if (tid < NB * HP) {
        ((float*)h14)[tid] = 0.f;
        ((float*)h24)[tid] = 0.f;
    }
    if (tid < HP) ((float*)wlin4)[tid] = (tid < Hs) ? W_lin[tid] : 0.f;
    if (tid == 0) blin_s = b_lin[0];

    float bsum1 = 0.f, bsum2 = 0.f, wih1 = 0.f;
    int b_up = 0, j_up = 0;
    if (tid < G4) {
        bsum1 = b_ih1[tid] + b_hh1[tid];
        bsum2 = b_ih2[tid] + b_hh2[tid];
        wih1  = W_ih1[tid];
        b_up = tid / Hs;
        j_up = tid - b_up * Hs;
    }
    float c1 = 0.f, c2 = 0.f;   // cell states for update cell (b_up, j_up)
    __syncthreads();

    for (int t = 0; t < Ts; ++t) {
        // ---- Phase A: layer-1 gate matvec || W_lin dot for t-1 ----
        if (tid < G4) {
            const float4* wr = w1L + tid * K4;
            float a0 = fmaf(wih1, xs[t][0], bsum1);
            float a1 = fmaf(wih1, xs[t][1], bsum1);
            float a2 = fmaf(wih1, xs[t][2], bsum1);
            float a3 = fmaf(wih1, xs[t][3], bsum1);
            #pragma unroll
            for (int k = 0; k < K4; ++k) {
                float4 w  = wr[k];
                float4 h0 = h14[0][k];
                float4 h1 = h14[1][k];
                float4 h2 = h14[2][k];
                float4 h3 = h14[3][k];
                a0 = fmaf(w.x, h0.x, a0); a0 = fmaf(w.y, h0.y, a0);
                a0 = fmaf(w.z, h0.z, a0); a0 = fmaf(w.w, h0.w, a0);
                a1 = fmaf(w.x, h1.x, a1); a1 = fmaf(w.y, h1.y, a1);
                a1 = fmaf(w.z, h1.z, a1); a1 = fmaf(w.w, h1.w, a1);
                a2 = fmaf(w.x, h2.x, a2); a2 = fmaf(w.y, h2.y, a2);
                a2 = fmaf(w.z, h2.z, a2); a2 = fmaf(w.w, h2.w, a2);
                a3 = fmaf(w.x, h3.x, a3); a3 = fmaf(w.y, h3.y, a3);
                a3 = fmaf(w.z, h3.z, a3); a3 = fmaf(w.w, h3.w, a3);
            }
            gs[0][tid] = a0; gs[1][tid] = a1;
            gs[2][tid] = a2; gs[3][tid] = a3;
        } else if (t > 0 && tid < G4 + NB) {
            int b = tid - G4;
            float s = blin_s;
            #pragma unroll
            for (int k = 0; k < K4; ++k) {
                float4 hh = h24[b][k];
                float4 w  = wlin4[k];
                s += hh.x * w.x + hh.y * w.y + hh.z * w.z + hh.w * w.w;
            }
            out[(bg0 + b) * Ts + (t - 1)] = s;
        }
        __syncthreads();

        // ---- Phase B: layer-1 elementwise update (204 threads) ----
        if (tid < G4) {
            float gi = gs[b_up][j_up];
            float gf = gs[b_up][Hs + j_up];
            float gg = gs[b_up][2 * Hs + j_up];
            float go = gs[b_up][3 * Hs + j_up];
            float iv = sig_(gi);
            float fv = sig_(gf);
            float gv = tanh_(gg);
            float ov = sig_(go);
            c1 = fmaf(fv, c1, iv * gv);
            ((float*)&h14[b_up][0])[j_up] = ov * tanh_(c1);
        }
        __syncthreads();

        // ---- Phase C: layer-2 gate matvec ----
        if (tid < G4) {
            const float4* ur = w2L + tid * K4;
            const float4* vr = w3L + tid * K4;
            float a0 = bsum2, a1 = bsum2, a2 = bsum2, a3 = bsum2;
            #pragma unroll
            for (int k = 0; k < K4; ++k) {
                float4 u  = ur[k];
                float4 v  = vr[k];
                float4 p0 = h14[0][k];
                float4 p1 = h14[1][k];
                float4 p2 = h14[2][k];
                float4 p3 = h14[3][k];
                float4 q0 = h24[0][k];
                float4 q1 = h24[1][k];
                float4 q2 = h24[2][k];
                float4 q3 = h24[3][k];
                a0 = fmaf(u.x, p0.x, a0); a0 = fmaf(u.y, p0.y, a0);
                a0 = fmaf(u.z, p0.z, a0); a0 = fmaf(u.w, p0.w, a0);
                a0 = fmaf(v.x, q0.x, a0); a0 = fmaf(v.y, q0.y, a0);
                a0 = fmaf(v.z, q0.z, a0); a0 = fmaf(v.w, q0.w, a0);
                a1 = fmaf(u.x, p1.x, a1); a1 = fmaf(u.y, p1.y, a1);
                a1 = fmaf(u.z, p1.z, a1); a1 = fmaf(u.w, p1.w, a1);
                a1 = fmaf(v.x, q1.x, a1); a1 = fmaf(v.y, q1.y, a1);
                a1 = fmaf(v.z, q1.z, a1); a1 = fmaf(v.w, q1.w, a1);
                a2 = fmaf(u.x, p2.x, a2); a2 = fmaf(u.y, p2.y, a2);
                a2 = fmaf(u.z, p2.z, a2); a2 = fmaf(u.w, p2.w, a2);
                a2 = fmaf(v.x, q2.x, a2); a2 = fmaf(v.y, q2.y, a2);
                a2 = fmaf(v.z, q2.z, a2); a2 = fmaf(v.w, q2.w, a2);
                a3 = fmaf(u.x, p3.x, a3); a3 = fmaf(u.y, p3.y, a3);
                a3 = fmaf(u.z, p3.z, a3); a3 = fmaf(u.w, p3.w, a3);
                a3 = fmaf(v.x, q3.x, a3); a3 = fmaf(v.y, q3.y, a3);
                a3 = fmaf(v.z, q3.z, a3); a3 = fmaf(v.w, q3.w, a3);
            }
            gs[0][tid] = a0; gs[1][tid] = a1;
            gs[2][tid] = a2; gs[3][tid] = a3;
        }
        __syncthreads();

        // ---- Phase D: layer-2 elementwise update ----
        if (tid < G4) {
            float gi = gs[b_up][j_up];
            float gf = gs[b_up][Hs + j_up];
            float gg = gs[b_up][2 * Hs + j_up];
            float go = gs[b_up][3 * Hs + j_up];
            float iv = sig_(gi);
            float fv = sig_(gf);
            float gv = tanh_(gg);
            float ov = sig_(go);
            c2 = fmaf(fv, c2, iv * gv);
            ((float*)&h24[b_up][0])[j_up] = ov * tanh_(c2);
        }
        __syncthreads();
    }

    // ---- final output for t = T-1 ----
    if (tid >= G4 && tid < G4 + NB) {
        int b = tid - G4;
        float s = blin_s;
        #pragma unroll
        for (int k = 0; k < K4; ++k) {
            float4 hh = h24[b][k];
            float4 w  = wlin4[k];
            s += hh.x * w.x + hh.y * w.y + hh.z * w.z + hh.w * w.w;
        }
        out[(bg0 + b) * Ts + (Ts - 1)] = s;
    }
}

extern "C" void kernel_launch(void* const* d_in, const int* in_sizes, int n_in,
                              void* d_out, int out_size, void* d_ws, size_t ws_size,
                              hipStream_t stream) {
    const float* x     = (const float*)d_in[0];
    const float* W_ih1 = (const float*)d_in[1];
    const float* W_hh1 = (const float*)d_in[2];
    const float* b_ih1 = (const float*)d_in[3];
    const float* b_hh1 = (const float*)d_in[4];
    const float* W_ih2 = (const float*)d_in[5];
    const float* W_hh2 = (const float*)d_in[6];
    const float* b_ih2 = (const float*)d_in[7];
    const float* b_hh2 = (const float*)d_in[8];
    const float* W_lin = (const float*)d_in[9];
    const float* b_lin = (const float*)d_in[10];
    float* out = (float*)d_out;

    lstm2_kernel<<<Bs / NB, NT, 0, stream>>>(
        x, W_ih1, W_hh1, b_ih1, b_hh1,
        W_ih2, W_hh2, b_ih2, b_hh2, W_lin, b_lin, out);
}

// Round 6
// 1583.592 us; speedup vs baseline: 1.1761x; 1.1761x over previous
//
#include <hip/hip_runtime.h>

// LSTM_26912265077001: 2-layer LSTM (H=51, IN=1), T=512, B=1024, fp32.
// R6: readlane-based h distribution + k-split across waves.
//   R5 calibrated the LDS model: ds_read_b128 ~12 cyc EVEN FOR BROADCAST
//   (R5: 780 b128/CU/step * 12 = 9360 cyc ~ measured 8730). h-broadcast was
//   the invariant ~6-7.5K cyc/step floor of R1-R5. This kernel distributes h
//   via ONE packed ds_read_b128 per wave + v_readlane (SGPR broadcast,
//   exec-agnostic), and splits the k-dimension across the 4 waves (wave w
//   owns k = 4*kk+w) so the readlane stream per SIMD is 1/4. Partial gate
//   sums are reduced through LDS by the update threads. Weights stay in
//   VGPRs: 156 floats/thread, pressure ~226 << 512 budget at waves(1,1),
//   so the R1-R4 spill motive (occupancy chasing at pressure>budget) is gone.
// Grid 256 blocks (1/CU), 256 threads (4 waves), NB=4 batches/block.

#define Hs   51
#define G4   204
#define Ts   512
#define Bs   1024
#define NB   4
#define NT   256

__device__ __forceinline__ float sig_(float x) {
    return 1.0f / (1.0f + __expf(-x));
}
__device__ __forceinline__ float tanh_(float x) {
    float e = __expf(2.0f * x);
    return 1.0f - 2.0f / (e + 1.0f);
}

// broadcast h[k=sel][b] from the packed quad via readlane (sel is wave-uniform)
#define RLF(v, sel) __uint_as_float(__builtin_amdgcn_readlane(__float_as_uint(v), (sel)))

__global__ void
__attribute__((amdgpu_flat_work_group_size(NT, NT), amdgpu_waves_per_eu(1, 1)))
lstm2_kernel(
    const float* __restrict__ x,      // (T, B, 1)
    const float* __restrict__ W_ih1,  // (204, 1)
    const float* __restrict__ W_hh1,  // (204, 51)
    const float* __restrict__ b_ih1,  // (204,)
    const float* __restrict__ b_hh1,  // (204,)
    const float* __restrict__ W_ih2,  // (204, 51)
    const float* __restrict__ W_hh2,  // (204, 51)
    const float* __restrict__ b_ih2,  // (204,)
    const float* __restrict__ b_hh2,  // (204,)
    const float* __restrict__ W_lin,  // (1, 51)
    const float* __restrict__ b_lin,  // (1,)
    float* __restrict__ out)          // (B, T)
{
    __shared__ float  hpT1[64 * 4];   // h1 packed [k][b]; k>=51 stays 0
    __shared__ float  hpT2[64 * 4];   // h2 packed [k][b]
    __shared__ float  h2a[NB][52];    // h2 row-major copy for the W_lin dot
    __shared__ float4 gsp4[4][256];   // per-wave partial gates [wave][row].b
    __shared__ float4 xs4[Ts];        // x[t][0..3]
    __shared__ float  wlin_s[52];
    __shared__ float  blin_s;

    const int tid  = threadIdx.x;
    const int lane = tid & 63;
    const int wv   = tid >> 6;
    const int bg0  = blockIdx.x * NB;

    // ---- one-time staging ----
    for (int idx = tid; idx < Ts * NB; idx += NT) {
        int t = idx >> 2, b = idx & 3;
        ((float*)xs4)[idx] = x[t * Bs + bg0 + b];
    }
    hpT1[tid] = 0.f;                  // tid in [0,256): covers pads k>=51 forever
    hpT2[tid] = 0.f;
    if (tid < NB * 52) ((float*)h2a)[tid] = 0.f;
    if (tid < 52) wlin_s[tid] = (tid < Hs) ? W_lin[tid] : 0.f;
    if (tid == 0) blin_s = b_lin[0];

    // ---- weights: this thread owns rows r = lane + 64*s, k = 4*kk + wv ----
    float w1a[4][13], w2a[4][13], w3a[4][13];
    #pragma unroll
    for (int s = 0; s < 4; ++s) {
        int r = lane + 64 * s;
        bool rv = (r < G4);
        #pragma unroll
        for (int kk = 0; kk < 13; ++kk) {
            int k = 4 * kk + wv;
            bool ok = rv && (k < Hs);
            w1a[s][kk] = ok ? W_hh1[r * Hs + k] : 0.f;
            w2a[s][kk] = ok ? W_ih2[r * Hs + k] : 0.f;
            w3a[s][kk] = ok ? W_hh2[r * Hs + k] : 0.f;
        }
    }

    // ---- update-thread constants (tid < 204 -> cell (bu, ju)) ----
    float bsA[4] = {0,0,0,0}, wiA[4] = {0,0,0,0}, bsC[4] = {0,0,0,0};
    int bu = 0, ju = 0;
    if (tid < G4) {
        bu = tid / Hs; ju = tid - bu * Hs;
        #pragma unroll
        for (int g = 0; g < 4; ++g) {
            int r = ju + g * Hs;
            bsA[g] = b_ih1[r] + b_hh1[r];
            wiA[g] = W_ih1[r];
            bsC[g] = b_ih2[r] + b_hh2[r];
        }
    }
    float c1 = 0.f, c2 = 0.f;
    const int w0 = __builtin_amdgcn_readfirstlane(wv);
    __syncthreads();

    for (int t = 0; t < Ts; ++t) {
        // ---- Phase A: partial W_hh1 . h1 over this wave's k-slice ----
        {
            float4 hq = *(const float4*)&hpT1[4 * lane];  // h1[k=lane][0..3]
            float acc[4][4];
            #pragma unroll
            for (int s = 0; s < 4; ++s)
                #pragma unroll
                for (int b = 0; b < 4; ++b) acc[s][b] = 0.f;
            #pragma unroll
            for (int kk = 0; kk < 13; ++kk) {
                int sel = 4 * kk + w0;
                float h0 = RLF(hq.x, sel);
                float h1 = RLF(hq.y, sel);
                float h2 = RLF(hq.z, sel);
                float h3 = RLF(hq.w, sel);
                #pragma unroll
                for (int s = 0; s < 4; ++s) {
                    float w = w1a[s][kk];
                    acc[s][0] = fmaf(w, h0, acc[s][0]);
                    acc[s][1] = fmaf(w, h1, acc[s][1]);
                    acc[s][2] = fmaf(w, h2, acc[s][2]);
                    acc[s][3] = fmaf(w, h3, acc[s][3]);
                }
            }
            #pragma unroll
            for (int s = 0; s < 4; ++s)
                gsp4[wv][lane + 64 * s] =
                    make_float4(acc[s][0], acc[s][1], acc[s][2], acc[s][3]);
        }
        __syncthreads();

        // ---- Phase B: layer-1 update (tid<204) || out-dot t-1 (tid 204..207) ----
        if (tid < G4) {
            float x_t = ((const float*)&xs4[t])[bu];
            float g[4];
            #pragma unroll
            for (int gg = 0; gg < 4; ++gg) {
                int row = ju + gg * Hs;
                float s = fmaf(wiA[gg], x_t, bsA[gg]);
                #pragma unroll
                for (int w = 0; w < 4; ++w)
                    s += ((const float*)gsp4)[(w * 256 + row) * 4 + bu];
                g[gg] = s;
            }
            float iv = sig_(g[0]), fv = sig_(g[1]);
            float gv = tanh_(g[2]), ov = sig_(g[3]);
            c1 = fmaf(fv, c1, iv * gv);
            hpT1[ju * 4 + bu] = ov * tanh_(c1);
        } else if (t > 0 && tid < G4 + NB) {
            int b = tid - G4;
            float s = blin_s;
            #pragma unroll
            for (int k4 = 0; k4 < 13; ++k4) {
                float4 hh = *(const float4*)&h2a[b][4 * k4];
                float4 ww = *(const float4*)&wlin_s[4 * k4];
                s += hh.x * ww.x + hh.y * ww.y + hh.z * ww.z + hh.w * ww.w;
            }
            out[(bg0 + b) * Ts + (t - 1)] = s;
        }
        __syncthreads();

        // ---- Phase C: partial W_ih2 . h1 + W_hh2 . h2 over k-slice ----
        {
            float4 ha = *(const float4*)&hpT1[4 * lane];  // h1(t)
            float4 hb = *(const float4*)&hpT2[4 * lane];  // h2(t-1)
            float acc[4][4];
            #pragma unroll
            for (int s = 0; s < 4; ++s)
                #pragma unroll
                for (int b = 0; b < 4; ++b) acc[s][b] = 0.f;
            #pragma unroll
            for (int kk = 0; kk < 13; ++kk) {
                int sel = 4 * kk + w0;
                float p0 = RLF(ha.x, sel);
                float p1 = RLF(ha.y, sel);
                float p2 = RLF(ha.z, sel);
                float p3 = RLF(ha.w, sel);
                float q0 = RLF(hb.x, sel);
                float q1 = RLF(hb.y, sel);
                float q2 = RLF(hb.z, sel);
                float q3 = RLF(hb.w, sel);
                #pragma unroll
                for (int s = 0; s < 4; ++s) {
                    float u = w2a[s][kk];
                    float v = w3a[s][kk];
                    acc[s][0] = fmaf(u, p0, acc[s][0]);
                    acc[s][1] = fmaf(u, p1, acc[s][1]);
                    acc[s][2] = fmaf(u, p2, acc[s][2]);
                    acc[s][3] = fmaf(u, p3, acc[s][3]);
                    acc[s][0] = fmaf(v, q0, acc[s][0]);
                    acc[s][1] = fmaf(v, q1, acc[s][1]);
                    acc[s][2] = fmaf(v, q2, acc[s][2]);
                    acc[s][3] = fmaf(v, q3, acc[s][3]);
                }
            }
            #pragma unroll
            for (int s = 0; s < 4; ++s)
                gsp4[wv][lane + 64 * s] =
                    make_float4(acc[s][0], acc[s][1], acc[s][2], acc[s][3]);
        }
        __syncthreads();

        // ---- Phase D: layer-2 update ----
        if (tid < G4) {
            float g[4];
            #pragma unroll
            for (int gg = 0; gg < 4; ++gg) {
                int row = ju + gg * Hs;
                float s = bsC[gg];
                #pragma unroll
                for (int w = 0; w < 4; ++w)
                    s += ((const float*)gsp4)[(w * 256 + row) * 4 + bu];
                g[gg] = s;
            }
            float iv = sig_(g[0]), fv = sig_(g[1]);
            float gv = tanh_(g[2]), ov = sig_(g[3]);
            c2 = fmaf(fv, c2, iv * gv);
            float h2v = ov * tanh_(c2);
            hpT2[ju * 4 + bu] = h2v;
            h2a[bu][ju] = h2v;
        }
        __syncthreads();
    }

    // ---- final output for t = T-1 ----
    if (tid >= G4 && tid < G4 + NB) {
        int b = tid - G4;
        float s = blin_s;
        #pragma unroll
        for (int k4 = 0; k4 < 13; ++k4) {
            float4 hh = *(const float4*)&h2a[b][4 * k4];
            float4 ww = *(const float4*)&wlin_s[4 * k4];
            s += hh.x * ww.x + hh.y * ww.y + hh.z * ww.z + hh.w * ww.w;
        }
        out[(bg0 + b) * Ts + (Ts - 1)] = s;
    }
}

extern "C" void kernel_launch(void* const* d_in, const int* in_sizes, int n_in,
                              void* d_out, int out_size, void* d_ws, size_t ws_size,
                              hipStream_t stream) {
    const float* x     = (const float*)d_in[0];
    const float* W_ih1 = (const float*)d_in[1];
    const float* W_hh1 = (const float*)d_in[2];
    const float* b_ih1 = (const float*)d_in[3];
    const float* b_hh1 = (const float*)d_in[4];
    const float* W_ih2 = (const float*)d_in[5];
    const float* W_hh2 = (const float*)d_in[6];
    const float* b_ih2 = (const float*)d_in[7];
    const float* b_hh2 = (const float*)d_in[8];
    const float* W_lin = (const float*)d_in[9];
    const float* b_lin = (const float*)d_in[10];
    float* out = (float*)d_out;

    lstm2_kernel<<<Bs / NB, NT, 0, stream>>>(
        x, W_ih1, W_hh1, b_ih1, b_hh1,
        W_ih2, W_hh2, b_ih2, b_hh2, W_lin, b_lin, out);
}